// Round 1
// baseline (397.996 us; speedup 1.0000x reference)
//
#include <hip/hip_runtime.h>
#include <stdint.h>

#define BB 128
#define NN 32768
#define CI 6
#define TOPK 400
#define KEEPK 200
#define SORTN 512
#define THREADS 256

// ---------------- Kernel 1: masked score keys ----------------
// key = float bits of score if score > 0.5 else 0. Scores > 0.5 are positive,
// so uint bit pattern is order-isomorphic to float value.
__global__ void key_kernel(const float* __restrict__ pred, uint32_t* __restrict__ keys) {
    const int total = BB * NN;
    for (int i = blockIdx.x * blockDim.x + threadIdx.x; i < total;
         i += gridDim.x * blockDim.x) {
        const float2 c = *reinterpret_cast<const float2*>(pred + (size_t)i * CI + 4);
        float s = fmaxf(c.x, c.y);
        keys[i] = (s > 0.5f) ? __float_as_uint(s) : 0u;
    }
}

// ---------------- Kernel 2: per-image select + NMS + output ----------------
__global__ __launch_bounds__(THREADS) void select_kernel(
        const float* __restrict__ pred, const float* __restrict__ priors,
        const uint32_t* __restrict__ keys, float* __restrict__ out) {
    const int b = blockIdx.x;
    const int tid = threadIdx.x;
    const uint32_t* k = keys + (size_t)b * NN;
    float* oimg = out + (size_t)b * KEEPK * 6;

    __shared__ unsigned int hist[2048];
    __shared__ unsigned int part[THREADS];
    __shared__ unsigned int sh_bucket, sh_above;
    __shared__ unsigned long long cbuf[SORTN];
    __shared__ float cx1[TOPK], cy1[TOPK], cx2[TOPK], cy2[TOPK], csc[TOPK], car[TOPK];
    __shared__ int clab[TOPK], ckeep[TOPK];
    __shared__ unsigned int ccount;

    // zero the output rows for this image (d_out is poisoned before each launch)
    for (int i = tid; i < KEEPK * 6; i += THREADS) oimg[i] = 0.0f;

    // ---- 3-level radix select: find T = 400th largest key (bits 31:21, 20:10, 9:0)
    unsigned int prefix = 0;
    unsigned int tgt = TOPK;
    for (int level = 0; level < 3; level++) {
        for (int i = tid; i < 2048; i += THREADS) hist[i] = 0;
        __syncthreads();
        for (int i = tid; i < NN; i += THREADS) {
            uint32_t key = k[i];
            unsigned int bucket; bool match;
            if (level == 0)      { match = true;                       bucket = key >> 21; }
            else if (level == 1) { match = ((key >> 21) == prefix);    bucket = (key >> 10) & 0x7FFu; }
            else                 { match = ((key >> 10) == prefix);    bucket = key & 0x3FFu; }
            if (match) atomicAdd(&hist[bucket], 1u);
        }
        __syncthreads();
        // per-thread chunk sums (8 buckets each), then suffix sums
        unsigned int s = 0;
#pragma unroll
        for (int j = 0; j < 8; j++) s += hist[tid * 8 + j];
        part[tid] = s;
        __syncthreads();
        unsigned int P = 0;
        for (int u = tid + 1; u < THREADS; u++) P += part[u];
        // walk own chunk from top; exactly one bucket satisfies above < tgt <= above+h
        unsigned int acc = P;
#pragma unroll
        for (int j = 7; j >= 0; j--) {
            unsigned int h = hist[tid * 8 + j];
            if (acc < tgt && acc + h >= tgt) { sh_bucket = (unsigned int)(tid * 8 + j); sh_above = acc; }
            acc += h;
        }
        __syncthreads();
        unsigned int bsel = sh_bucket;
        unsigned int above = sh_above;
        __syncthreads();
        if (level == 0)      prefix = bsel;
        else if (level == 1) prefix = (prefix << 11) | bsel;
        else                 prefix = (prefix << 10) | bsel;
        tgt -= above;
    }
    const uint32_t T = prefix;  // threshold key (the 400th largest key value)

    // ---- gather all keys >= T as composite (key, ~idx); sort desc => exact top_k order
    if (tid == 0) ccount = 0;
    for (int i = tid; i < SORTN; i += THREADS) cbuf[i] = 0ull;
    __syncthreads();
    for (int i = tid; i < NN; i += THREADS) {
        uint32_t key = k[i];
        if (key >= T && key != 0u) {
            unsigned int p = atomicAdd(&ccount, 1u);
            if (p < SORTN)
                cbuf[p] = ((unsigned long long)key << 32) | (unsigned long long)(0xFFFFFFFFu - (uint32_t)i);
        }
    }
    __syncthreads();

    // ---- bitonic sort, 512 elements, descending
    for (int kk = 2; kk <= SORTN; kk <<= 1) {
        for (int j = kk >> 1; j > 0; j >>= 1) {
            for (int i = tid; i < SORTN; i += THREADS) {
                int partner = i ^ j;
                if (partner > i) {
                    unsigned long long a = cbuf[i], c = cbuf[partner];
                    bool descBlock = ((i & kk) == 0);
                    bool doSwap = descBlock ? (a < c) : (a > c);
                    if (doSwap) { cbuf[i] = c; cbuf[partner] = a; }
                }
            }
            __syncthreads();
        }
    }

    // ---- decode the 400 candidates (replicate reference float op order; no fma)
    for (int t = tid; t < TOPK; t += THREADS) {
        unsigned long long c = cbuf[t];
        uint32_t key = (uint32_t)(c >> 32);
        uint32_t idx = 0xFFFFFFFFu - (uint32_t)(c & 0xFFFFFFFFull);
        float score = __uint_as_float(key);
        int valid = (key != 0u) && (idx < NN);
        float x1 = 0.f, y1 = 0.f, x2 = 0.f, y2 = 0.f;
        int lab = 0;
        if (valid) {
            const float* p = pred + ((size_t)b * NN + idx) * CI;
            float l0 = p[0], l1 = p[1], l2 = p[2], l3 = p[3], c0 = p[4], c1 = p[5];
            const float* pr = priors + (size_t)idx * 4;
            float px = pr[0], py = pr[1], pw = pr[2], ph = pr[3];
            float tx = __fmul_rn(__fmul_rn(l0, 0.1f), pw);
            float ty = __fmul_rn(__fmul_rn(l1, 0.1f), ph);
            float cxv = __fadd_rn(px, tx);
            float cyv = __fadd_rn(py, ty);
            float ew = __fmul_rn(pw, expf(__fmul_rn(l2, 0.2f)));
            float eh = __fmul_rn(ph, expf(__fmul_rn(l3, 0.2f)));
            float hw = __fmul_rn(ew, 0.5f);
            float hh = __fmul_rn(eh, 0.5f);
            x1 = __fsub_rn(cxv, hw); y1 = __fsub_rn(cyv, hh);
            x2 = __fadd_rn(cxv, hw); y2 = __fadd_rn(cyv, hh);
            lab = (c1 > c0) ? 1 : 0;
        }
        cx1[t] = x1; cy1[t] = y1; cx2[t] = x2; cy2[t] = y2;
        csc[t] = score;
        car[t] = __fmul_rn(__fsub_rn(x2, x1), __fsub_rn(y2, y1));
        clab[t] = lab;
        ckeep[t] = valid;
    }
    __syncthreads();

    // ---- sequential NMS (reference fori_loop semantics)
    for (int i = 0; i < TOPK; i++) {
        if (ckeep[i]) {  // uniform: all threads read same LDS value
            float bx1 = cx1[i], by1 = cy1[i], bx2 = cx2[i], by2 = cy2[i], ba = car[i];
            for (int j = i + 1 + tid; j < TOPK; j += THREADS) {
                if (ckeep[j]) {
                    float iw = fmaxf(__fsub_rn(fminf(bx2, cx2[j]), fmaxf(bx1, cx1[j])), 0.0f);
                    float ih = fmaxf(__fsub_rn(fminf(by2, cy2[j]), fmaxf(by1, cy1[j])), 0.0f);
                    float inter = __fmul_rn(iw, ih);
                    float denom = __fadd_rn(__fsub_rn(__fadd_rn(ba, car[j]), inter), 1e-12f);
                    float iou = __fdiv_rn(inter, denom);
                    if (iou > 0.5f) ckeep[j] = 0;
                }
            }
            __syncthreads();
        }
    }
    __syncthreads();

    // ---- output: kept candidates sorted ascending by (score, position), first 200 rows
    for (int t = tid; t < TOPK; t += THREADS) {
        if (ckeep[t]) {
            float st = csc[t];
            int rank = 0;
            for (int j = 0; j < TOPK; j++) {
                if (ckeep[j] && (csc[j] < st || (csc[j] == st && j < t))) rank++;
            }
            if (rank < KEEPK) {
                float* row = oimg + (size_t)rank * 6;
                row[0] = (float)clab[t];
                row[1] = st;
                row[2] = cx1[t]; row[3] = cy1[t];
                row[4] = cx2[t]; row[5] = cy2[t];
            }
        }
    }
}

extern "C" void kernel_launch(void* const* d_in, const int* in_sizes, int n_in,
                              void* d_out, int out_size, void* d_ws, size_t ws_size,
                              hipStream_t stream) {
    const float* pred = (const float*)d_in[0];     // (128, 32768, 6)
    const float* priors = (const float*)d_in[1];   // (32768, 4)
    float* out = (float*)d_out;                    // (128, 200, 6)
    uint32_t* keys = (uint32_t*)d_ws;              // B*N uint32 = 16.8 MB

    key_kernel<<<2048, THREADS, 0, stream>>>(pred, keys);
    select_kernel<<<BB, THREADS, 0, stream>>>(pred, priors, keys, out);
}

// Round 2
// 338.079 us; speedup vs baseline: 1.1772x; 1.1772x over previous
//
#include <hip/hip_runtime.h>
#include <stdint.h>

#define BB 128
#define NN 32768
#define CI 6
#define TOPK 400
#define KEEPK 200
#define SORTN 512
#define THREADS 256

// ---------------- Kernel 1: masked score keys (LDS-staged, coalesced) ------
// key = float bits of score if score > 0.5 else 0 (positive floats: bit
// pattern is order-isomorphic to value).
__global__ __launch_bounds__(THREADS) void key_kernel(
        const float* __restrict__ pred, uint32_t* __restrict__ keys) {
    __shared__ float tile[6144];                       // 1024 rows x 6 floats
    const int tid = threadIdx.x;
    const size_t rbase = (size_t)blockIdx.x * 1024;    // grid = 4096 blocks
    const float4* src = reinterpret_cast<const float4*>(pred + rbase * CI);
#pragma unroll
    for (int r = 0; r < 6; r++)
        reinterpret_cast<float4*>(tile)[tid + THREADS * r] = src[tid + THREADS * r];
    __syncthreads();
    uint32_t* kout = keys + rbase;
#pragma unroll
    for (int r = 0; r < 4; r++) {
        int row = tid + THREADS * r;                   // rows t, t+256, ... (4-way LDS conflict max)
        float2 c = *reinterpret_cast<const float2*>(&tile[6 * row + 4]);
        float s = fmaxf(c.x, c.y);
        kout[row] = (s > 0.5f) ? __float_as_uint(s) : 0u;
    }
}

// ---------------- Kernel 2: per-image select + NMS + output ----------------
__global__ __launch_bounds__(THREADS, 1) void select_kernel(
        const float* __restrict__ pred, const float* __restrict__ priors,
        const uint32_t* __restrict__ keys, float* __restrict__ out) {
    const int b = blockIdx.x;
    const int tid = threadIdx.x;
    const uint32_t* k = keys + (size_t)b * NN;
    float* oimg = out + (size_t)b * KEEPK * 6;

    __shared__ unsigned int hist[2048];
    __shared__ unsigned int part[THREADS];
    __shared__ unsigned int sh_bucket, sh_above, ccount;
    __shared__ unsigned long long cbuf[SORTN];
    __shared__ float4 cbox[TOPK];
    __shared__ float car[TOPK], csc[TOPK];
    __shared__ int clab[TOPK];
    __shared__ unsigned long long supm[TOPK * 8];      // 7 used words + 1 pad per row
    __shared__ unsigned long long keepw[8];

    // zero output rows (d_out poisoned before every launch)
    for (int i = tid; i < KEEPK * 6; i += THREADS) oimg[i] = 0.0f;

    // ---- single global read: all 32768 keys into registers (128/thread)
    uint32_t kreg[128];
#pragma unroll
    for (int t = 0; t < 128; t++) kreg[t] = k[tid + (t << 8)];

    // ---- 3-level radix select for T = 400th largest key (bits 31:21,20:10,9:0)
    unsigned int prefix = 0, tgt = TOPK;
    for (int level = 0; level < 3; level++) {
        for (int i = tid; i < 2048; i += THREADS) hist[i] = 0;
        __syncthreads();
#pragma unroll
        for (int t = 0; t < 128; t++) {
            uint32_t key = kreg[t];
            unsigned int bucket; bool match;
            if (level == 0)      { match = (key != 0u);             bucket = key >> 21; }
            else if (level == 1) { match = ((key >> 21) == prefix); bucket = (key >> 10) & 0x7FFu; }
            else                 { match = ((key >> 10) == prefix); bucket = key & 0x3FFu; }
            if (match) atomicAdd(&hist[bucket], 1u);
        }
        __syncthreads();
        unsigned int s = 0;
#pragma unroll
        for (int j = 0; j < 8; j++) s += hist[tid * 8 + j];
        part[tid] = s;
        __syncthreads();
        // parallel inclusive suffix-sum of part[]
        for (int st = 1; st < THREADS; st <<= 1) {
            unsigned int v = part[tid];
            if (tid + st < THREADS) v += part[tid + st];
            __syncthreads();
            part[tid] = v;
            __syncthreads();
        }
        unsigned int P = part[tid] - s;   // sum over threads above mine
        unsigned int acc = P;
#pragma unroll
        for (int j = 7; j >= 0; j--) {
            unsigned int h = hist[tid * 8 + j];
            if (acc < tgt && acc + h >= tgt) { sh_bucket = (unsigned int)(tid * 8 + j); sh_above = acc; }
            acc += h;
        }
        __syncthreads();
        unsigned int bsel = sh_bucket, above = sh_above;
        __syncthreads();
        if (level == 0)      prefix = bsel;
        else if (level == 1) prefix = (prefix << 11) | bsel;
        else                 prefix = (prefix << 10) | bsel;
        tgt -= above;
    }
    const uint32_t T = prefix;

    // ---- gather composites (key, ~idx) for keys >= T, from registers
    if (tid == 0) ccount = 0;
    for (int i = tid; i < SORTN; i += THREADS) cbuf[i] = 0ull;
    if (tid < 8) keepw[tid] = 0ull;
    __syncthreads();
#pragma unroll
    for (int t = 0; t < 128; t++) {
        uint32_t key = kreg[t];
        if (key >= T && key != 0u) {
            unsigned int p = atomicAdd(&ccount, 1u);
            if (p < SORTN) {
                unsigned int idx = (unsigned int)tid + ((unsigned int)t << 8);
                cbuf[p] = ((unsigned long long)key << 32) |
                          (unsigned long long)(0xFFFFFFFFu - idx);
            }
        }
    }
    __syncthreads();

    // ---- bitonic sort 512 desc => exact top_k order (ties: smaller idx first)
    for (int kk = 2; kk <= SORTN; kk <<= 1) {
        for (int j = kk >> 1; j > 0; j >>= 1) {
            for (int i = tid; i < SORTN; i += THREADS) {
                int partner = i ^ j;
                if (partner > i) {
                    unsigned long long a = cbuf[i], c = cbuf[partner];
                    bool descBlock = ((i & kk) == 0);
                    if (descBlock ? (a < c) : (a > c)) { cbuf[i] = c; cbuf[partner] = a; }
                }
            }
            __syncthreads();
        }
    }

    // ---- decode candidates (replicate reference float op order; no fma)
    for (int t = tid; t < TOPK; t += THREADS) {
        unsigned long long c = cbuf[t];
        uint32_t key = (uint32_t)(c >> 32);
        uint32_t idx = 0xFFFFFFFFu - (uint32_t)(c & 0xFFFFFFFFull);
        int valid = (key != 0u) && (idx < NN);
        float x1 = 0.f, y1 = 0.f, x2 = 0.f, y2 = 0.f;
        int lab = 0;
        if (valid) {
            const float* p = pred + ((size_t)b * NN + idx) * CI;
            float l0 = p[0], l1 = p[1], l2 = p[2], l3 = p[3], c0 = p[4], c1 = p[5];
            const float* pr = priors + (size_t)idx * 4;
            float px = pr[0], py = pr[1], pw = pr[2], ph = pr[3];
            float cxv = __fadd_rn(px, __fmul_rn(__fmul_rn(l0, 0.1f), pw));
            float cyv = __fadd_rn(py, __fmul_rn(__fmul_rn(l1, 0.1f), ph));
            float ew = __fmul_rn(pw, expf(__fmul_rn(l2, 0.2f)));
            float eh = __fmul_rn(ph, expf(__fmul_rn(l3, 0.2f)));
            float hw = __fmul_rn(ew, 0.5f);
            float hh = __fmul_rn(eh, 0.5f);
            x1 = __fsub_rn(cxv, hw); y1 = __fsub_rn(cyv, hh);
            x2 = __fadd_rn(cxv, hw); y2 = __fadd_rn(cyv, hh);
            lab = (c1 > c0) ? 1 : 0;
        }
        cbox[t] = make_float4(x1, y1, x2, y2);
        csc[t] = __uint_as_float(key);
        car[t] = __fmul_rn(__fsub_rn(x2, x1), __fsub_rn(y2, y1));
        clab[t] = lab;
        if (valid) atomicOr(&keepw[t >> 6], 1ull << (t & 63));
    }
    __syncthreads();

    // ---- suppression bit-matrix: supm[i][w] bit jj = (iou(i, 64w+jj)>0.5 && j>i)
    for (int w4 = 0; w4 < 7; w4++) {
        const int jbase = w4 << 6;
        const int jmax = (TOPK - jbase < 64) ? (TOPK - jbase) : 64;
        for (int i = tid; i < TOPK; i += THREADS) {
            unsigned long long word = 0ull;
            if (jbase + jmax > i + 1) {           // word contains some j > i
                float4 bi = cbox[i]; float ai = car[i];
                for (int jj = 0; jj < jmax; jj++) {   // cbox[j]: same addr all lanes -> broadcast
                    int j = jbase + jj;
                    float4 bj = cbox[j]; float aj = car[j];
                    float iw = fmaxf(__fsub_rn(fminf(bi.z, bj.z), fmaxf(bi.x, bj.x)), 0.0f);
                    float ih = fmaxf(__fsub_rn(fminf(bi.w, bj.w), fmaxf(bi.y, bj.y)), 0.0f);
                    float inter = __fmul_rn(iw, ih);
                    float denom = __fadd_rn(__fsub_rn(__fadd_rn(ai, aj), inter), 1e-12f);
                    float iou = __fdiv_rn(inter, denom);
                    if (iou > 0.5f && j > i) word |= (1ull << jj);
                }
            }
            supm[i * 8 + w4] = word;
        }
    }
    __syncthreads();

    // ---- sequential resolve in one wave; keep bits in registers, rows prefetched
    if (tid < 64) {
        int w = tid & 7;                          // lanes 0-6 own words; others shadow
        unsigned long long kw = keepw[w];
        unsigned long long nxt = supm[w];         // prefetch row 0
        for (int i = 0; i < TOPK; i++) {
            unsigned long long cur = nxt;
            int ni = (i + 1 < TOPK) ? (i + 1) : i;
            nxt = supm[ni * 8 + w];
            unsigned long long wv = __shfl(kw, i >> 6);
            if ((wv >> (i & 63)) & 1ull) kw &= ~cur;
        }
        if (tid < 7) keepw[tid] = kw;
    }
    __syncthreads();

    // ---- output: kept sorted ascending by (score, position), first 200 rows
    for (int t = tid; t < TOPK; t += THREADS) {
        if ((keepw[t >> 6] >> (t & 63)) & 1ull) {
            float st = csc[t];
            int rank = 0;
            for (int j = 0; j < TOPK; j++) {
                bool kj = (keepw[j >> 6] >> (j & 63)) & 1ull;
                float sj = csc[j];
                if (kj && (sj < st || (sj == st && j < t))) rank++;
            }
            if (rank < KEEPK) {
                float4 bx = cbox[t];
                float* row = oimg + (size_t)rank * 6;
                row[0] = (float)clab[t];
                row[1] = st;
                row[2] = bx.x; row[3] = bx.y; row[4] = bx.z; row[5] = bx.w;
            }
        }
    }
}

extern "C" void kernel_launch(void* const* d_in, const int* in_sizes, int n_in,
                              void* d_out, int out_size, void* d_ws, size_t ws_size,
                              hipStream_t stream) {
    const float* pred = (const float*)d_in[0];     // (128, 32768, 6)
    const float* priors = (const float*)d_in[1];   // (32768, 4)
    float* out = (float*)d_out;                    // (128, 200, 6)
    uint32_t* keys = (uint32_t*)d_ws;              // B*N uint32 = 16.8 MB

    key_kernel<<<(BB * NN) / 1024, THREADS, 0, stream>>>(pred, keys);
    select_kernel<<<BB, THREADS, 0, stream>>>(pred, priors, keys, out);
}

// Round 3
// 254.108 us; speedup vs baseline: 1.5663x; 1.3305x over previous
//
#include <hip/hip_runtime.h>
#include <stdint.h>

#define BB 128
#define NN 32768
#define CI 6
#define TOPK 400
#define KEEPK 200
#define SORTN 512
#define NT 1024
#define KPT 32   // keys per thread = NN / NT

// One block per image: keys -> radix-select top-400 threshold -> gather ->
// bitonic sort (exact reference order) -> decode -> NMS bit-matrix ->
// sequential resolve -> rank + output. All numerics replicate the reference
// float op sequence (no fma contraction) for decision-exactness.
__global__ __launch_bounds__(NT) void boxsel_kernel(
        const float* __restrict__ pred, const float* __restrict__ priors,
        float* __restrict__ out) {
    const int b = blockIdx.x;
    const int tid = threadIdx.x;
    const int lane = tid & 63;
    const int wid = tid >> 6;                 // 0..15
    const float* img = pred + (size_t)b * (NN * CI);
    float* oimg = out + (size_t)b * KEEPK * 6;

    __shared__ unsigned int hist[2][2048];    // 2 copies to cut atomic chains
    __shared__ unsigned int wavetot[16];
    __shared__ unsigned int sh_bucket, sh_above, ccount;
    __shared__ unsigned long long cbuf[SORTN];
    __shared__ float4 cbox[TOPK];
    __shared__ float car[TOPK], csc[TOPK];
    __shared__ int clab[TOPK];
    __shared__ unsigned long long supm[TOPK * 7 + 8];  // stride 7 + pad
    __shared__ unsigned long long keepw[8];

    // zero output rows (d_out poisoned before every launch)
    for (int i = tid; i < KEEPK * 6; i += NT) oimg[i] = 0.0f;

    // ---- phase 1: conf pairs -> masked score keys, register-resident
    // key = float bits of score if score > 0.5 else 0 (positive floats:
    // bit pattern order-isomorphic to value).
    uint32_t kreg[KPT];
#pragma unroll
    for (int u = 0; u < KPT; u++) {
        int r = tid + (u << 10);
        float2 c = *reinterpret_cast<const float2*>(img + 6 * r + 4);
        float s = fmaxf(c.x, c.y);
        kreg[u] = (s > 0.5f) ? __float_as_uint(s) : 0u;
    }

    // ---- phase 2: 3-level radix select for T = 400th largest key
    // (bits 31:21, 20:10, 9:0)
    unsigned int prefix = 0, tgt = TOPK;
    const int hc = wid & 1;
    for (int level = 0; level < 3; level++) {
        for (int i = tid; i < 4096; i += NT) ((unsigned int*)hist)[i] = 0;
        __syncthreads();
#pragma unroll
        for (int u = 0; u < KPT; u++) {
            uint32_t key = kreg[u];
            unsigned int bucket; bool match;
            if (level == 0)      { match = (key != 0u);             bucket = key >> 21; }
            else if (level == 1) { match = ((key >> 21) == prefix); bucket = (key >> 10) & 0x7FFu; }
            else                 { match = ((key >> 10) == prefix); bucket = key & 0x3FFu; }
            if (match) atomicAdd(&hist[hc][bucket], 1u);
        }
        __syncthreads();
        // merge copies; thread owns buckets 2tid, 2tid+1
        unsigned int h0 = hist[0][2 * tid] + hist[1][2 * tid];
        unsigned int h1 = hist[0][2 * tid + 1] + hist[1][2 * tid + 1];
        unsigned int s = h0 + h1;
        // wave-level inclusive suffix sum (higher lane = higher buckets)
        unsigned int suf = s;
#pragma unroll
        for (int off = 1; off < 64; off <<= 1) {
            unsigned int v = __shfl_down(suf, off);
            if (lane + off < 64) suf += v;
        }
        if (lane == 0) wavetot[wid] = suf;
        __syncthreads();
        if (tid < 16) {                       // exclusive suffix over waves
            unsigned int wv = wavetot[tid];
            unsigned int ws = wv;
#pragma unroll
            for (int off = 1; off < 16; off <<= 1) {
                unsigned int v = __shfl_down(ws, off);
                if (tid + off < 16) ws += v;
            }
            wavetot[tid] = ws - wv;
        }
        __syncthreads();
        unsigned int acc = wavetot[wid] + (suf - s);  // count strictly above my chunk
        if (acc < tgt && acc + h1 >= tgt) { sh_bucket = 2 * tid + 1; sh_above = acc; }
        acc += h1;
        if (acc < tgt && acc + h0 >= tgt) { sh_bucket = 2 * tid; sh_above = acc; }
        __syncthreads();
        unsigned int bsel = sh_bucket, above = sh_above;
        __syncthreads();
        if (level == 0)      prefix = bsel;
        else if (level == 1) prefix = (prefix << 11) | bsel;
        else                 prefix = (prefix << 10) | bsel;
        tgt -= above;
    }
    const uint32_t T = prefix;

    // ---- phase 3: gather composites (key, ~idx) for keys >= T
    if (tid == 0) ccount = 0;
    if (tid < SORTN) cbuf[tid] = 0ull;
    if (tid < 8) keepw[tid] = 0ull;
    __syncthreads();
#pragma unroll
    for (int u = 0; u < KPT; u++) {
        uint32_t key = kreg[u];
        if (key >= T && key != 0u) {
            unsigned int p = atomicAdd(&ccount, 1u);
            if (p < SORTN) {
                unsigned int idx = (unsigned int)tid + ((unsigned int)u << 10);
                cbuf[p] = ((unsigned long long)key << 32) |
                          (unsigned long long)(0xFFFFFFFFu - idx);
            }
        }
    }
    __syncthreads();

    // ---- phase 4: bitonic sort 512 desc => exact top_k order (ties: lower idx)
    for (int kk = 2; kk <= SORTN; kk <<= 1) {
        for (int j = kk >> 1; j > 0; j >>= 1) {
            if (tid < SORTN) {
                int partner = tid ^ j;
                if (partner > tid) {
                    unsigned long long a = cbuf[tid], c = cbuf[partner];
                    if (((tid & kk) == 0) ? (a < c) : (a > c)) {
                        cbuf[tid] = c; cbuf[partner] = a;
                    }
                }
            }
            __syncthreads();
        }
    }

    // ---- phase 5: decode candidates (reference float op order; no fma)
    if (tid < TOPK) {
        const int t = tid;
        unsigned long long c = cbuf[t];
        uint32_t key = (uint32_t)(c >> 32);
        uint32_t idx = 0xFFFFFFFFu - (uint32_t)(c & 0xFFFFFFFFull);
        int valid = (key != 0u) && (idx < NN);
        float x1 = 0.f, y1 = 0.f, x2 = 0.f, y2 = 0.f;
        int lab = 0;
        if (valid) {
            const float* p = img + (size_t)idx * CI;
            float l0 = p[0], l1 = p[1], l2 = p[2], l3 = p[3], c0 = p[4], c1 = p[5];
            const float* pr = priors + (size_t)idx * 4;
            float px = pr[0], py = pr[1], pw = pr[2], ph = pr[3];
            float cxv = __fadd_rn(px, __fmul_rn(__fmul_rn(l0, 0.1f), pw));
            float cyv = __fadd_rn(py, __fmul_rn(__fmul_rn(l1, 0.1f), ph));
            float ew = __fmul_rn(pw, expf(__fmul_rn(l2, 0.2f)));
            float eh = __fmul_rn(ph, expf(__fmul_rn(l3, 0.2f)));
            float hw = __fmul_rn(ew, 0.5f);
            float hh = __fmul_rn(eh, 0.5f);
            x1 = __fsub_rn(cxv, hw); y1 = __fsub_rn(cyv, hh);
            x2 = __fadd_rn(cxv, hw); y2 = __fadd_rn(cyv, hh);
            lab = (c1 > c0) ? 1 : 0;
        }
        cbox[t] = make_float4(x1, y1, x2, y2);
        csc[t] = __uint_as_float(key);
        car[t] = __fmul_rn(__fsub_rn(x2, x1), __fsub_rn(y2, y1));
        clab[t] = lab;
        if (valid) atomicOr(&keepw[t >> 6], 1ull << (t & 63));
    }
    __syncthreads();

    // ---- phase 6: suppression bit-matrix, upper triangle only
    for (int task = tid; task < TOPK * 7; task += NT) {
        int i = task / 7;
        int w4 = task - i * 7;
        int jbase = w4 << 6;
        int jmax = (TOPK - jbase < 64) ? (TOPK - jbase) : 64;
        int j0 = i + 1 - jbase; if (j0 < 0) j0 = 0;
        unsigned long long word = 0ull;
        if (j0 < jmax) {
            float4 bi = cbox[i]; float ai = car[i];
            for (int jj = j0; jj < jmax; jj++) {   // cbox[j]: broadcast reads
                int j = jbase + jj;
                float4 bj = cbox[j]; float aj = car[j];
                float iw = fmaxf(__fsub_rn(fminf(bi.z, bj.z), fmaxf(bi.x, bj.x)), 0.0f);
                float ih = fmaxf(__fsub_rn(fminf(bi.w, bj.w), fmaxf(bi.y, bj.y)), 0.0f);
                float inter = __fmul_rn(iw, ih);
                float denom = __fadd_rn(__fsub_rn(__fadd_rn(ai, aj), inter), 1e-12f);
                float iou = __fdiv_rn(inter, denom);
                if (iou > 0.5f) word |= (1ull << jj);
            }
        }
        supm[i * 7 + w4] = word;
    }
    __syncthreads();

    // ---- phase 7: sequential resolve in one wave, keep bits in registers
    if (tid < 64) {
        int w = tid & 7;                     // lanes 0-6 own words; rest shadow
        unsigned long long kw = keepw[w];
        unsigned long long nxt = supm[w];    // prefetch row 0 (w=7 reads pad)
        for (int i = 0; i < TOPK; i++) {
            unsigned long long cur = nxt;
            int ni = (i + 1 < TOPK) ? (i + 1) : i;
            nxt = supm[ni * 7 + w];
            unsigned long long wv = __shfl(kw, i >> 6);
            if ((wv >> (i & 63)) & 1ull) kw &= ~cur;
        }
        if (tid < 7) keepw[tid] = kw;
    }
    __syncthreads();

    // ---- phase 8: kept sorted ascending by (score, position), first 200 rows
    if (tid < TOPK) {
        const int t = tid;
        if ((keepw[t >> 6] >> (t & 63)) & 1ull) {
            float st = csc[t];
            int rank = 0;
            for (int j = 0; j < TOPK; j++) {
                bool kj = (keepw[j >> 6] >> (j & 63)) & 1ull;
                float sj = csc[j];
                if (kj && (sj < st || (sj == st && j < t))) rank++;
            }
            if (rank < KEEPK) {
                float4 bx = cbox[t];
                float* row = oimg + (size_t)rank * 6;
                row[0] = (float)clab[t];
                row[1] = st;
                row[2] = bx.x; row[3] = bx.y; row[4] = bx.z; row[5] = bx.w;
            }
        }
    }
}

extern "C" void kernel_launch(void* const* d_in, const int* in_sizes, int n_in,
                              void* d_out, int out_size, void* d_ws, size_t ws_size,
                              hipStream_t stream) {
    const float* pred = (const float*)d_in[0];     // (128, 32768, 6)
    const float* priors = (const float*)d_in[1];   // (32768, 4)
    float* out = (float*)d_out;                    // (128, 200, 6)
    boxsel_kernel<<<BB, NT, 0, stream>>>(pred, priors, out);
}